// Round 4
// baseline (227.138 us; speedup 1.0000x reference)
//
#include <hip/hip_runtime.h>

#define T_TOK 200
#define EMB   128
#define S_TILE 8
#define NT    512
#define LPAD  4

// ---- Weight transpose/pack: Wt[fc][o] = float4{ W[o][4fc..4fc+3] } ----
// W1t: ws4[0:16384)  (fc<32, FOUT=512)
// W2t: ws4[16384:49152) (fc<128, FOUT=256)
// W3t: ws4[49152:57344) (fc<64, FOUT=128)
__global__ __launch_bounds__(256) void transpose_w(
    const float* __restrict__ W1, const float* __restrict__ W2,
    const float* __restrict__ W3, float4* __restrict__ ws4)
{
    int j = blockIdx.x * 256 + threadIdx.x;
    if (j < 16384) {
        int fc = j >> 9, o = j & 511;
        const float* s = W1 + (size_t)o * 128 + fc * 4;
        ws4[fc * 512 + o] = make_float4(s[0], s[1], s[2], s[3]);
    } else if (j < 49152) {
        int t = j - 16384;
        int fc = t >> 8, o = t & 255;
        const float* s = W2 + (size_t)o * 512 + fc * 4;
        ws4[16384 + fc * 256 + o] = make_float4(s[0], s[1], s[2], s[3]);
    } else if (j < 57344) {
        int t = j - 49152;
        int fc = t >> 7, o = t & 127;
        const float* s = W3 + (size_t)o * 256 + fc * 4;
        ws4[49152 + fc * 128 + o] = make_float4(s[0], s[1], s[2], s[3]);
    }
}

// ---- layer with transposed-packed W: coalesced 16B/lane W loads,
//      double-buffered 4-chunk batches ----
template <int FIN, int FOUT, bool RELU>
__device__ __forceinline__ void layerT(const float* __restrict__ sin,
                                       float* __restrict__ sout,
                                       const float4* __restrict__ Wt,
                                       const float* __restrict__ b, int tid)
{
    constexpr int SIN_STR  = FIN + LPAD;
    constexpr int SOUT_STR = FOUT + LPAD;
    constexpr int NO     = (FOUT < NT) ? FOUT : NT;
    constexpr int GROUPS = NT / NO;
    constexpr int SPT    = S_TILE / GROUPS;
    constexpr int NB     = FIN / 16;          // 16 floats of W per batch

    const int o0 = tid % NO;
    const int s0 = (tid / NO) * SPT;

    float acc[SPT];
    {
        float bi = b[o0];
#pragma unroll
        for (int j = 0; j < SPT; ++j) acc[j] = bi;
    }

    float4 wa[4], wb[4];

    auto loadW = [&](int bidx, float4 w[4]) {
#pragma unroll
        for (int c = 0; c < 4; ++c)
            w[c] = Wt[(size_t)(bidx * 4 + c) * FOUT + o0];   // 16B/lane coalesced
    };
    auto consumeW = [&](const float4 w[4], int bidx) {
#pragma unroll
        for (int j = 0; j < SPT; ++j) {
#pragma unroll
            for (int c = 0; c < 4; ++c) {
                float4 xv = *(const float4*)&sin[(s0 + j) * SIN_STR + bidx * 16 + c * 4];
                acc[j] = fmaf(xv.x, w[c].x, acc[j]);
                acc[j] = fmaf(xv.y, w[c].y, acc[j]);
                acc[j] = fmaf(xv.z, w[c].z, acc[j]);
                acc[j] = fmaf(xv.w, w[c].w, acc[j]);
            }
        }
    };

    loadW(0, wa);
    for (int b2 = 1; b2 < NB; ++b2) {
        if (b2 & 1) { loadW(b2, wb); consumeW(wa, b2 - 1); }
        else        { loadW(b2, wa); consumeW(wb, b2 - 1); }
    }
    if (NB & 1) consumeW(wa, NB - 1); else consumeW(wb, NB - 1);

#pragma unroll
    for (int j = 0; j < SPT; ++j) {
        float v = acc[j];
        if (RELU) v = fmaxf(v, 0.f);
        sout[(s0 + j) * SOUT_STR + o0] = v;
    }
}

// ---- Fused pool + MLP: 512 threads = 8 waves, 8 samples/block ----
__global__ __launch_bounds__(NT, 4) void fused_kernel(
    const int* __restrict__ x, const int* __restrict__ lengths,
    const float* __restrict__ emb,
    const float4* __restrict__ ws4,
    const float* __restrict__ b1, const float* __restrict__ b2,
    const float* __restrict__ b3,
    const float* __restrict__ W4, const float* __restrict__ b4,
    float* __restrict__ out)
{
    __shared__ float bufA[S_TILE * (256 + LPAD)];   // X (str 132), H2 (str 260)
    __shared__ float bufB[S_TILE * (512 + LPAD)];   // H1 (str 516), H3 (str 132)

    const int tid  = threadIdx.x;
    const int wid  = tid >> 6;           // 0..7, one sample per wave
    const int lane = tid & 63;
    const int base = blockIdx.x * S_TILE;
    const int half = lane >> 5;          // 0 = even token of pair, 1 = odd
    const int col4 = (lane & 31) * 4;

    // ---- pool phase ----
    {
        const int n   = base + wid;
        const int len = lengths[n];
        const int* xr = x + (size_t)n * T_TOK;

        int r0 = xr[lane];
        int r1 = xr[64 + lane];
        int r2 = xr[128 + lane];
        int r3 = xr[(192 + lane < T_TOK) ? (192 + lane) : (T_TOK - 1)];

        float4 acc  = make_float4(0.f, 0.f, 0.f, 0.f);
        float4 acc2 = make_float4(0.f, 0.f, 0.f, 0.f);

        auto pickR = [&](int t0) {
            int c = t0 >> 6;
            int r = r0;
            if (c == 1) r = r1;
            if (c == 2) r = r2;
            if (c == 3) r = r3;
            return r;
        };
        // full batch: 16 tokens as 8 pair-loads (2 rows per dwordx4 wave-load)
        auto loadF = [&](int t0, float4 v[8]) {
            int r = pickR(t0), kk = t0 & 63;
#pragma unroll
            for (int i = 0; i < 8; ++i) {
                int idx = __shfl(r, kk + 2 * i + half);
                v[i] = *(const float4*)(emb + (size_t)idx * EMB + col4);
            }
        };
        auto consumeF = [&](const float4 v[8]) {
#pragma unroll
            for (int i = 0; i < 8; ++i) {
                if (i & 1) { acc2.x += v[i].x; acc2.y += v[i].y; acc2.z += v[i].z; acc2.w += v[i].w; }
                else       { acc.x  += v[i].x; acc.y  += v[i].y; acc.z  += v[i].z; acc.w  += v[i].w; }
            }
        };

        const int nfb  = len >> 4;          // full 16-token batches
        const int tail = len - (nfb << 4);

        float4 va[8], vb[8];
        if (nfb) {
            loadF(0, va);
            for (int b2v = 1; b2v < nfb; ++b2v) {
                if (b2v & 1) { loadF(b2v * 16, vb); consumeF(va); }
                else         { loadF(b2v * 16, va); consumeF(vb); }
            }
            if (nfb & 1) consumeF(va); else consumeF(vb);
        }
        if (tail) {
            const int t0 = nfb << 4;
            int r = pickR(t0), kk = t0 & 63;
            float4 vt[8];
#pragma unroll
            for (int i = 0; i < 8; ++i) {
                if (2 * i < tail) {            // wave-uniform: skip unused pairs
                    int idx = __shfl(r, kk + 2 * i + half);
                    vt[i] = *(const float4*)(emb + (size_t)idx * EMB + col4);
                } else vt[i] = make_float4(0.f, 0.f, 0.f, 0.f);
            }
#pragma unroll
            for (int i = 0; i < 8; ++i) {
                if (2 * i + half < tail) {     // boundary pair: per-lane predicate
                    acc.x += vt[i].x; acc.y += vt[i].y;
                    acc.z += vt[i].z; acc.w += vt[i].w;
                }
            }
        }

        acc.x += acc2.x; acc.y += acc2.y; acc.z += acc2.z; acc.w += acc2.w;
        acc.x += __shfl(acc.x, lane ^ 32);
        acc.y += __shfl(acc.y, lane ^ 32);
        acc.z += __shfl(acc.z, lane ^ 32);
        acc.w += __shfl(acc.w, lane ^ 32);

        if (half == 0) {
            const float inv = 1.0f / (float)len;
            *(float4*)&bufA[wid * (EMB + LPAD) + col4] =
                make_float4(acc.x * inv, acc.y * inv, acc.z * inv, acc.w * inv);
        }
    }
    __syncthreads();

    // ---- MLP phase (transposed-packed W in ws4) ----
    layerT<128, 512, true>(bufA, bufB, ws4,         b1, tid);
    __syncthreads();
    layerT<512, 256, true>(bufB, bufA, ws4 + 16384, b2, tid);
    __syncthreads();
    layerT<256, 128, true>(bufA, bufB, ws4 + 49152, b3, tid);
    __syncthreads();

    if (tid < 2 * S_TILE) {
        int s = tid >> 1;
        int o = tid & 1;
        float accv = b4[o];
        const float* xr2 = &bufB[s * (EMB + LPAD)];
        const float* wr2 = &W4[(size_t)o * EMB];
#pragma unroll 8
        for (int f = 0; f < EMB; ++f) accv = fmaf(xr2[f], wr2[f], accv);
        out[(size_t)(base + s) * 2 + o] = accv;
    }
}

extern "C" void kernel_launch(void* const* d_in, const int* in_sizes, int n_in,
                              void* d_out, int out_size, void* d_ws, size_t ws_size,
                              hipStream_t stream)
{
    const int*   x       = (const int*)d_in[0];
    const int*   lengths = (const int*)d_in[1];
    const float* emb     = (const float*)d_in[2];
    const float* W1      = (const float*)d_in[3];
    const float* b1      = (const float*)d_in[4];
    const float* W2      = (const float*)d_in[5];
    const float* b2      = (const float*)d_in[6];
    const float* W3      = (const float*)d_in[7];
    const float* b3      = (const float*)d_in[8];
    const float* W4      = (const float*)d_in[9];
    const float* b4      = (const float*)d_in[10];
    float*       out     = (float*)d_out;
    float4*      ws4     = (float4*)d_ws;        // 57344 float4 = 896 KB

    const int N = in_sizes[1];   // 4096

    transpose_w<<<224, 256, 0, stream>>>(W1, W2, W3, ws4);
    fused_kernel<<<N / S_TILE, NT, 0, stream>>>(x, lengths, emb, ws4,
                                                b1, b2, b3, W4, b4, out);
}

// Round 6
// 177.185 us; speedup vs baseline: 1.2819x; 1.2819x over previous
//
#include <hip/hip_runtime.h>

#define T_TOK 200
#define EMB   128
#define S_TILE 8
#define LPAD  4

// ---- Weight transpose/pack: Wt[fc][o] = float4{ W[o][4fc..4fc+3] } ----
// Wt1: ws4[0:16384)      (fc<32,  FOUT=512)
// Wt2: ws4[16384:49152)  (fc<128, FOUT=256)
// Wt3: ws4[49152:57344)  (fc<64,  FOUT=128)
// Proven correct in R4 (passed, absmax 6.1e-5).
__global__ __launch_bounds__(256) void transpose_w(
    const float* __restrict__ W1, const float* __restrict__ W2,
    const float* __restrict__ W3, float4* __restrict__ ws4)
{
    int j = blockIdx.x * 256 + threadIdx.x;       // 224*256 = 57344 exact
    if (j < 16384) {
        int fc = j >> 9, o = j & 511;
        const float* s = W1 + (size_t)o * 128 + fc * 4;
        ws4[fc * 512 + o] = make_float4(s[0], s[1], s[2], s[3]);
    } else if (j < 49152) {
        int t = j - 16384;
        int fc = t >> 8, o = t & 255;
        const float* s = W2 + (size_t)o * 512 + fc * 4;
        ws4[16384 + fc * 256 + o] = make_float4(s[0], s[1], s[2], s[3]);
    } else {
        int t = j - 49152;
        int fc = t >> 7, o = t & 127;
        const float* s = W3 + (size_t)o * 256 + fc * 4;
        ws4[49152 + fc * 128 + o] = make_float4(s[0], s[1], s[2], s[3]);
    }
}

// ---- layer with transposed-packed W at 256 threads ----
// W loads are 16B/lane fully coalesced (consecutive o across lanes), one
// chunk prefetched ahead. Register cost: wc+wn = 8*OPT + acc OPT*SPT <= 48.
template <int FIN, int FOUT, bool RELU>
__device__ __forceinline__ void layerT(const float* __restrict__ sin,
                                       float* __restrict__ sout,
                                       const float4* __restrict__ Wt,
                                       const float* __restrict__ b, int tid)
{
    constexpr int SIN_STR  = FIN + LPAD;
    constexpr int SOUT_STR = FOUT + LPAD;
    constexpr int NO     = (FOUT < 256) ? FOUT : 256;
    constexpr int OPT    = FOUT / NO;            // 512->2, else 1
    constexpr int GROUPS = 256 / NO;
    constexpr int SPT    = S_TILE / GROUPS;

    const int o0 = tid & (NO - 1);
    const int s0 = (tid / NO) * SPT;

    float acc[OPT][SPT];
#pragma unroll
    for (int i = 0; i < OPT; ++i) {
        float bi = b[o0 + i * NO];
#pragma unroll
        for (int j = 0; j < SPT; ++j) acc[i][j] = bi;
    }

    float4 wc[OPT], wn[OPT];
#pragma unroll
    for (int i = 0; i < OPT; ++i) wc[i] = Wt[(size_t)0 * FOUT + o0 + i * NO];

    int f = 0;
    for (; f < FIN - 4; f += 4) {
        const int fc = (f >> 2) + 1;
#pragma unroll
        for (int i = 0; i < OPT; ++i) wn[i] = Wt[(size_t)fc * FOUT + o0 + i * NO];
#pragma unroll
        for (int j = 0; j < SPT; ++j) {
            float4 xv = *(const float4*)&sin[(s0 + j) * SIN_STR + f];
#pragma unroll
            for (int i = 0; i < OPT; ++i) {
                acc[i][j] = fmaf(xv.x, wc[i].x, acc[i][j]);
                acc[i][j] = fmaf(xv.y, wc[i].y, acc[i][j]);
                acc[i][j] = fmaf(xv.z, wc[i].z, acc[i][j]);
                acc[i][j] = fmaf(xv.w, wc[i].w, acc[i][j]);
            }
        }
#pragma unroll
        for (int i = 0; i < OPT; ++i) wc[i] = wn[i];
    }
#pragma unroll
    for (int j = 0; j < SPT; ++j) {
        float4 xv = *(const float4*)&sin[(s0 + j) * SIN_STR + f];
#pragma unroll
        for (int i = 0; i < OPT; ++i) {
            acc[i][j] = fmaf(xv.x, wc[i].x, acc[i][j]);
            acc[i][j] = fmaf(xv.y, wc[i].y, acc[i][j]);
            acc[i][j] = fmaf(xv.z, wc[i].z, acc[i][j]);
            acc[i][j] = fmaf(xv.w, wc[i].w, acc[i][j]);
        }
    }

#pragma unroll
    for (int j = 0; j < SPT; ++j) {
#pragma unroll
        for (int i = 0; i < OPT; ++i) {
            float v = acc[i][j];
            if (RELU) v = fmaxf(v, 0.f);
            sout[(s0 + j) * SOUT_STR + o0 + i * NO] = v;
        }
    }
}

// ---- Fused pool + MLP: 256 threads = 4 waves, 8 samples/block (R3 pool) ----
__global__ __launch_bounds__(256) void fused_kernel(
    const int* __restrict__ x, const int* __restrict__ lengths,
    const float* __restrict__ emb,
    const float4* __restrict__ Wt,
    const float* __restrict__ b1, const float* __restrict__ b2,
    const float* __restrict__ b3,
    const float* __restrict__ W4, const float* __restrict__ b4,
    float* __restrict__ out)
{
    __shared__ float bufA[S_TILE * (256 + LPAD)];   // X (str 132), H2 (str 260)
    __shared__ float bufB[S_TILE * (512 + LPAD)];   // H1 (str 516), H3 (str 132)

    const int tid  = threadIdx.x;
    const int wid  = tid >> 6;
    const int lane = tid & 63;
    const int base = blockIdx.x * S_TILE;
    const int half = lane >> 5;          // 0 = even token of pair, 1 = odd
    const int col4 = (lane & 31) * 4;

    // ---- pool phase: wave wid pools samples 2*wid, 2*wid+1 (R3, proven) ----
    for (int sl = 0; sl < 2; ++sl) {
        const int s   = wid * 2 + sl;
        const int n   = base + s;
        const int len = lengths[n];
        const int* xr = x + (size_t)n * T_TOK;

        int r0 = xr[lane];
        int r1 = xr[64 + lane];
        int r2 = xr[128 + lane];
        int r3 = xr[(192 + lane < T_TOK) ? (192 + lane) : (T_TOK - 1)];

        float4 acc = make_float4(0.f, 0.f, 0.f, 0.f);

        for (int c = 0; c < 4; ++c) {
            const int coff = c * 64;
            if (coff >= len) break;
            int m = len - coff;
            if (m > 64) m = 64;
            int r = r0;
            if (c == 1) r = r1;
            if (c == 2) r = r2;
            if (c == 3) r = r3;

            for (int k = 0; k < m; k += 16) {   // 16 tokens as 8 pair-loads
                float4 v[8];
#pragma unroll
                for (int i = 0; i < 8; ++i) {
                    int idx = __shfl(r, k + 2 * i + half);
                    v[i] = *(const float4*)(emb + (size_t)idx * EMB + col4);
                }
#pragma unroll
                for (int i = 0; i < 8; ++i) {
                    int T = coff + k + 2 * i + half;
                    if (T < len) {
                        acc.x += v[i].x; acc.y += v[i].y;
                        acc.z += v[i].z; acc.w += v[i].w;
                    }
                }
            }
        }

        acc.x += __shfl(acc.x, lane ^ 32);
        acc.y += __shfl(acc.y, lane ^ 32);
        acc.z += __shfl(acc.z, lane ^ 32);
        acc.w += __shfl(acc.w, lane ^ 32);

        if (half == 0) {
            const float inv = 1.0f / (float)len;
            *(float4*)&bufA[s * (EMB + LPAD) + col4] =
                make_float4(acc.x * inv, acc.y * inv, acc.z * inv, acc.w * inv);
        }
    }
    __syncthreads();

    // ---- MLP phase: coalesced transposed-packed W ----
    layerT<128, 512, true>(bufA, bufB, Wt,         b1, tid);
    __syncthreads();
    layerT<512, 256, true>(bufB, bufA, Wt + 16384, b2, tid);
    __syncthreads();
    layerT<256, 128, true>(bufA, bufB, Wt + 49152, b3, tid);
    __syncthreads();

    if (tid < 2 * S_TILE) {
        int s = tid >> 1;
        int o = tid & 1;
        float accv = b4[o];
        const float* xr2 = &bufB[s * (EMB + LPAD)];
        const float* wr2 = &W4[(size_t)o * EMB];
#pragma unroll 8
        for (int f = 0; f < EMB; ++f) accv = fmaf(xr2[f], wr2[f], accv);
        out[(size_t)(base + s) * 2 + o] = accv;
    }
}

extern "C" void kernel_launch(void* const* d_in, const int* in_sizes, int n_in,
                              void* d_out, int out_size, void* d_ws, size_t ws_size,
                              hipStream_t stream)
{
    const int*   x       = (const int*)d_in[0];
    const int*   lengths = (const int*)d_in[1];
    const float* emb     = (const float*)d_in[2];
    const float* W1      = (const float*)d_in[3];
    const float* b1      = (const float*)d_in[4];
    const float* W2      = (const float*)d_in[5];
    const float* b2      = (const float*)d_in[6];
    const float* W3      = (const float*)d_in[7];
    const float* b3      = (const float*)d_in[8];
    const float* W4      = (const float*)d_in[9];
    const float* b4      = (const float*)d_in[10];
    float*       out     = (float*)d_out;
    float4*      Wt      = (float4*)d_ws;        // 57344 float4 = 896 KB

    const int N = in_sizes[1];   // 4096

    transpose_w<<<224, 256, 0, stream>>>(W1, W2, W3, Wt);
    fused_kernel<<<N / S_TILE, 256, 0, stream>>>(x, lengths, emb, Wt,
                                                 b1, b2, b3, W4, b4, out);
}

// Round 7
// 176.009 us; speedup vs baseline: 1.2905x; 1.0067x over previous
//
#include <hip/hip_runtime.h>

#define T_TOK 200
#define EMB   128
#define S_TILE 8
#define LPAD  4

// ---- Weight transpose/pack: Wt[fc][o] = float4{ W[o][4fc..4fc+3] } ----
// Wt1: ws4[0:16384)      (fc<32,  FOUT=512)
// Wt2: ws4[16384:49152)  (fc<128, FOUT=256)
// Wt3: ws4[49152:57344)  (fc<64,  FOUT=128)
__global__ __launch_bounds__(256) void transpose_w(
    const float* __restrict__ W1, const float* __restrict__ W2,
    const float* __restrict__ W3, float4* __restrict__ ws4)
{
    int j = blockIdx.x * 256 + threadIdx.x;       // 224*256 = 57344 exact
    if (j < 16384) {
        int fc = j >> 9, o = j & 511;
        const float* s = W1 + (size_t)o * 128 + fc * 4;
        ws4[fc * 512 + o] = make_float4(s[0], s[1], s[2], s[3]);
    } else if (j < 49152) {
        int t = j - 16384;
        int fc = t >> 8, o = t & 255;
        const float* s = W2 + (size_t)o * 512 + fc * 4;
        ws4[16384 + fc * 256 + o] = make_float4(s[0], s[1], s[2], s[3]);
    } else {
        int t = j - 49152;
        int fc = t >> 7, o = t & 127;
        const float* s = W3 + (size_t)o * 256 + fc * 4;
        ws4[49152 + fc * 128 + o] = make_float4(s[0], s[1], s[2], s[3]);
    }
}

// ---- layer with transposed-packed W, tunable outputs-per-thread (OPT) ----
// Higher OPT = more FMAs per LDS activation read (the R6 bottleneck).
// W loads stay 16B/lane coalesced: o = o0 + i*NO, o0 lane-consecutive.
// Per-wave LDS issue: L1 4xv/64FMA, L2 2xv/32FMA, L3 2xv/16FMA.
template <int FIN, int FOUT, int OPT, bool RELU>
__device__ __forceinline__ void layerT(const float* __restrict__ sin,
                                       float* __restrict__ sout,
                                       const float4* __restrict__ Wt,
                                       const float* __restrict__ b, int tid)
{
    constexpr int SIN_STR  = FIN + LPAD;
    constexpr int SOUT_STR = FOUT + LPAD;
    constexpr int NO     = FOUT / OPT;      // threads covering the o-dim
    constexpr int GROUPS = 256 / NO;
    constexpr int SPT    = S_TILE / GROUPS; // samples per thread

    const int o0 = tid % NO;
    const int s0 = (tid / NO) * SPT;

    float acc[OPT][SPT];
#pragma unroll
    for (int i = 0; i < OPT; ++i) {
        float bi = b[o0 + i * NO];
#pragma unroll
        for (int j = 0; j < SPT; ++j) acc[i][j] = bi;
    }

    float4 wc[OPT], wn[OPT];
#pragma unroll
    for (int i = 0; i < OPT; ++i) wc[i] = Wt[(size_t)0 * FOUT + o0 + i * NO];

    int f = 0;
    for (; f < FIN - 4; f += 4) {
        const int fc = (f >> 2) + 1;
#pragma unroll
        for (int i = 0; i < OPT; ++i) wn[i] = Wt[(size_t)fc * FOUT + o0 + i * NO];
#pragma unroll
        for (int j = 0; j < SPT; ++j) {
            float4 xv = *(const float4*)&sin[(s0 + j) * SIN_STR + f];
#pragma unroll
            for (int i = 0; i < OPT; ++i) {
                acc[i][j] = fmaf(xv.x, wc[i].x, acc[i][j]);
                acc[i][j] = fmaf(xv.y, wc[i].y, acc[i][j]);
                acc[i][j] = fmaf(xv.z, wc[i].z, acc[i][j]);
                acc[i][j] = fmaf(xv.w, wc[i].w, acc[i][j]);
            }
        }
#pragma unroll
        for (int i = 0; i < OPT; ++i) wc[i] = wn[i];
    }
#pragma unroll
    for (int j = 0; j < SPT; ++j) {
        float4 xv = *(const float4*)&sin[(s0 + j) * SIN_STR + f];
#pragma unroll
        for (int i = 0; i < OPT; ++i) {
            acc[i][j] = fmaf(xv.x, wc[i].x, acc[i][j]);
            acc[i][j] = fmaf(xv.y, wc[i].y, acc[i][j]);
            acc[i][j] = fmaf(xv.z, wc[i].z, acc[i][j]);
            acc[i][j] = fmaf(xv.w, wc[i].w, acc[i][j]);
        }
    }

#pragma unroll
    for (int j = 0; j < SPT; ++j) {
#pragma unroll
        for (int i = 0; i < OPT; ++i) {
            float v = acc[i][j];
            if (RELU) v = fmaxf(v, 0.f);
            sout[(s0 + j) * SOUT_STR + o0 + i * NO] = v;
        }
    }
}

// ---- Fused pool + MLP: 256 threads = 4 waves, 8 samples/block ----
__global__ __launch_bounds__(256) void fused_kernel(
    const int* __restrict__ x, const int* __restrict__ lengths,
    const float* __restrict__ emb,
    const float4* __restrict__ Wt,
    const float* __restrict__ b1, const float* __restrict__ b2,
    const float* __restrict__ b3,
    const float* __restrict__ W4, const float* __restrict__ b4,
    float* __restrict__ out)
{
    __shared__ float bufA[S_TILE * (256 + LPAD)];   // X (str 132), H2 (str 260)
    __shared__ float bufB[S_TILE * (512 + LPAD)];   // H1 (str 516), H3 (str 132)

    const int tid  = threadIdx.x;
    const int wid  = tid >> 6;
    const int lane = tid & 63;
    const int base = blockIdx.x * S_TILE;
    const int half = lane >> 5;          // 0 = even token of pair, 1 = odd
    const int col4 = (lane & 31) * 4;

    // ---- pool phase: wave wid pools samples 2*wid, 2*wid+1 (R3, proven) ----
    for (int sl = 0; sl < 2; ++sl) {
        const int s   = wid * 2 + sl;
        const int n   = base + s;
        const int len = lengths[n];
        const int* xr = x + (size_t)n * T_TOK;

        int r0 = xr[lane];
        int r1 = xr[64 + lane];
        int r2 = xr[128 + lane];
        int r3 = xr[(192 + lane < T_TOK) ? (192 + lane) : (T_TOK - 1)];

        float4 acc = make_float4(0.f, 0.f, 0.f, 0.f);

        for (int c = 0; c < 4; ++c) {
            const int coff = c * 64;
            if (coff >= len) break;
            int m = len - coff;
            if (m > 64) m = 64;
            int r = r0;
            if (c == 1) r = r1;
            if (c == 2) r = r2;
            if (c == 3) r = r3;

            for (int k = 0; k < m; k += 16) {   // 16 tokens as 8 pair-loads
                float4 v[8];
#pragma unroll
                for (int i = 0; i < 8; ++i) {
                    int idx = __shfl(r, k + 2 * i + half);
                    v[i] = *(const float4*)(emb + (size_t)idx * EMB + col4);
                }
#pragma unroll
                for (int i = 0; i < 8; ++i) {
                    int T = coff + k + 2 * i + half;
                    if (T < len) {
                        acc.x += v[i].x; acc.y += v[i].y;
                        acc.z += v[i].z; acc.w += v[i].w;
                    }
                }
            }
        }

        acc.x += __shfl(acc.x, lane ^ 32);
        acc.y += __shfl(acc.y, lane ^ 32);
        acc.z += __shfl(acc.z, lane ^ 32);
        acc.w += __shfl(acc.w, lane ^ 32);

        if (half == 0) {
            const float inv = 1.0f / (float)len;
            *(float4*)&bufA[s * (EMB + LPAD) + col4] =
                make_float4(acc.x * inv, acc.y * inv, acc.z * inv, acc.w * inv);
        }
    }
    __syncthreads();

    // ---- MLP phase: OPT tuned for FMA-per-LDS-read intensity ----
    layerT<128, 512, 4, true>(bufA, bufB, Wt,         b1, tid);
    __syncthreads();
    layerT<512, 256, 4, true>(bufB, bufA, Wt + 16384, b2, tid);
    __syncthreads();
    layerT<256, 128, 2, true>(bufA, bufB, Wt + 49152, b3, tid);
    __syncthreads();

    if (tid < 2 * S_TILE) {
        int s = tid >> 1;
        int o = tid & 1;
        float accv = b4[o];
        const float* xr2 = &bufB[s * (EMB + LPAD)];
        const float* wr2 = &W4[(size_t)o * EMB];
#pragma unroll 8
        for (int f = 0; f < EMB; ++f) accv = fmaf(xr2[f], wr2[f], accv);
        out[(size_t)(base + s) * 2 + o] = accv;
    }
}

extern "C" void kernel_launch(void* const* d_in, const int* in_sizes, int n_in,
                              void* d_out, int out_size, void* d_ws, size_t ws_size,
                              hipStream_t stream)
{
    const int*   x       = (const int*)d_in[0];
    const int*   lengths = (const int*)d_in[1];
    const float* emb     = (const float*)d_in[2];
    const float* W1      = (const float*)d_in[3];
    const float* b1      = (const float*)d_in[4];
    const float* W2      = (const float*)d_in[5];
    const float* b2      = (const float*)d_in[6];
    const float* W3      = (const float*)d_in[7];
    const float* b3      = (const float*)d_in[8];
    const float* W4      = (const float*)d_in[9];
    const float* b4      = (const float*)d_in[10];
    float*       out     = (float*)d_out;
    float4*      Wt      = (float4*)d_ws;        // 57344 float4 = 896 KB

    const int N = in_sizes[1];   // 4096

    transpose_w<<<224, 256, 0, stream>>>(W1, W2, W3, Wt);
    fused_kernel<<<N / S_TILE, 256, 0, stream>>>(x, lengths, emb, Wt,
                                                 b1, b2, b3, W4, b4, out);
}

// Round 8
// 174.903 us; speedup vs baseline: 1.2986x; 1.0063x over previous
//
#include <hip/hip_runtime.h>
#include <hip/hip_fp16.h>

#define T_TOK 200
#define EMB   128
#define S_TILE 8
#define LPAD  4

// ws layout: Wt (57344 float4 = 917504 B) | embH (100000*128*2 = 25600000 B)
#define WT_F4      57344
#define EMBH_OFF   917504UL
#define WS_NEED    (EMBH_OFF + 25600000UL)

// ---- prep: W transpose/pack + emb fp32->fp16 convert ----
// blocks [0,6250): convert 12.8M floats (8/thread, 16B ld/st)
// blocks [6250,6474): Wt[fc][o] = float4{ W[o][4fc..4fc+3] }  (R4/R6-proven)
__global__ __launch_bounds__(256) void prep_kernel(
    const float* __restrict__ emb,
    const float* __restrict__ W1, const float* __restrict__ W2,
    const float* __restrict__ W3,
    __half* __restrict__ embH, float4* __restrict__ ws4, int do_conv)
{
    int bid = blockIdx.x;
    if (bid < 6250) {
        if (!do_conv) return;
        size_t i = ((size_t)bid * 256 + threadIdx.x) * 8;   // 6250*256*8 = 12.8M exact
        float4 a = *(const float4*)(emb + i);
        float4 b = *(const float4*)(emb + i + 4);
        __half2 hh[4];
        hh[0] = __floats2half2_rn(a.x, a.y);
        hh[1] = __floats2half2_rn(a.z, a.w);
        hh[2] = __floats2half2_rn(b.x, b.y);
        hh[3] = __floats2half2_rn(b.z, b.w);
        *(float4*)(embH + i) = *(float4*)hh;
    } else {
        int j = (bid - 6250) * 256 + threadIdx.x;           // < 57344
        if (j < 16384) {
            int fc = j >> 9, o = j & 511;
            const float* s = W1 + (size_t)o * 128 + fc * 4;
            ws4[fc * 512 + o] = make_float4(s[0], s[1], s[2], s[3]);
        } else if (j < 49152) {
            int t = j - 16384;
            int fc = t >> 8, o = t & 255;
            const float* s = W2 + (size_t)o * 512 + fc * 4;
            ws4[16384 + fc * 256 + o] = make_float4(s[0], s[1], s[2], s[3]);
        } else {
            int t = j - 49152;
            int fc = t >> 7, o = t & 127;
            const float* s = W3 + (size_t)o * 256 + fc * 4;
            ws4[49152 + fc * 128 + o] = make_float4(s[0], s[1], s[2], s[3]);
        }
    }
}

// ---- layer with transposed-packed W, tunable outputs-per-thread (R7-proven) ----
template <int FIN, int FOUT, int OPT, bool RELU>
__device__ __forceinline__ void layerT(const float* __restrict__ sin,
                                       float* __restrict__ sout,
                                       const float4* __restrict__ Wt,
                                       const float* __restrict__ b, int tid)
{
    constexpr int SIN_STR  = FIN + LPAD;
    constexpr int SOUT_STR = FOUT + LPAD;
    constexpr int NO     = FOUT / OPT;
    constexpr int GROUPS = 256 / NO;
    constexpr int SPT    = S_TILE / GROUPS;

    const int o0 = tid % NO;
    const int s0 = (tid / NO) * SPT;

    float acc[OPT][SPT];
#pragma unroll
    for (int i = 0; i < OPT; ++i) {
        float bi = b[o0 + i * NO];
#pragma unroll
        for (int j = 0; j < SPT; ++j) acc[i][j] = bi;
    }

    float4 wc[OPT], wn[OPT];
#pragma unroll
    for (int i = 0; i < OPT; ++i) wc[i] = Wt[(size_t)0 * FOUT + o0 + i * NO];

    int f = 0;
    for (; f < FIN - 4; f += 4) {
        const int fc = (f >> 2) + 1;
#pragma unroll
        for (int i = 0; i < OPT; ++i) wn[i] = Wt[(size_t)fc * FOUT + o0 + i * NO];
#pragma unroll
        for (int j = 0; j < SPT; ++j) {
            float4 xv = *(const float4*)&sin[(s0 + j) * SIN_STR + f];
#pragma unroll
            for (int i = 0; i < OPT; ++i) {
                acc[i][j] = fmaf(xv.x, wc[i].x, acc[i][j]);
                acc[i][j] = fmaf(xv.y, wc[i].y, acc[i][j]);
                acc[i][j] = fmaf(xv.z, wc[i].z, acc[i][j]);
                acc[i][j] = fmaf(xv.w, wc[i].w, acc[i][j]);
            }
        }
#pragma unroll
        for (int i = 0; i < OPT; ++i) wc[i] = wn[i];
    }
#pragma unroll
    for (int j = 0; j < SPT; ++j) {
        float4 xv = *(const float4*)&sin[(s0 + j) * SIN_STR + f];
#pragma unroll
        for (int i = 0; i < OPT; ++i) {
            acc[i][j] = fmaf(xv.x, wc[i].x, acc[i][j]);
            acc[i][j] = fmaf(xv.y, wc[i].y, acc[i][j]);
            acc[i][j] = fmaf(xv.z, wc[i].z, acc[i][j]);
            acc[i][j] = fmaf(xv.w, wc[i].w, acc[i][j]);
        }
    }

#pragma unroll
    for (int j = 0; j < SPT; ++j) {
#pragma unroll
        for (int i = 0; i < OPT; ++i) {
            float v = acc[i][j];
            if (RELU) v = fmaxf(v, 0.f);
            sout[(s0 + j) * SOUT_STR + o0 + i * NO] = v;
        }
    }
}

// ---- Fused pool + MLP. USE_FP16: pool reads 256B fp16 rows from embH,
// one dwordx4 wave-load = 4 rows (part=lane>>4, sub=lane&15, 8 cols/lane).
// Over-length slots clamp to token m-1 (dup-line load, no extra HBM). ----
template <bool USE_FP16>
__global__ __launch_bounds__(256) void fused_kernel(
    const int* __restrict__ x, const int* __restrict__ lengths,
    const float* __restrict__ emb, const __half* __restrict__ embH,
    const float4* __restrict__ Wt,
    const float* __restrict__ b1, const float* __restrict__ b2,
    const float* __restrict__ b3,
    const float* __restrict__ W4, const float* __restrict__ b4,
    float* __restrict__ out)
{
    __shared__ float bufA[S_TILE * (256 + LPAD)];   // X (str 132), H2 (str 260)
    __shared__ float bufB[S_TILE * (512 + LPAD)];   // H1 (str 516), H3 (str 132)

    const int tid  = threadIdx.x;
    const int wid  = tid >> 6;
    const int lane = tid & 63;
    const int base = blockIdx.x * S_TILE;

    // ---- pool phase: wave wid pools samples 2*wid, 2*wid+1 ----
    for (int sl = 0; sl < 2; ++sl) {
        const int s   = wid * 2 + sl;
        const int n   = base + s;
        const int len = lengths[n];
        const int* xr = x + (size_t)n * T_TOK;

        int r0 = xr[lane];
        int r1 = xr[64 + lane];
        int r2 = xr[128 + lane];
        int r3 = xr[(192 + lane < T_TOK) ? (192 + lane) : (T_TOK - 1)];

        if (USE_FP16) {
            const int part = lane >> 4;          // token-of-quad
            const int sub  = lane & 15;          // cols [8*sub, 8*sub+8)
            float acc[8];
#pragma unroll
            for (int j = 0; j < 8; ++j) acc[j] = 0.f;

            for (int c = 0; c < 4; ++c) {
                const int coff = c * 64;
                if (coff >= len) break;
                int m = len - coff;
                if (m > 64) m = 64;
                int r = r0;
                if (c == 1) r = r1;
                if (c == 2) r = r2;
                if (c == 3) r = r3;

                for (int k = 0; k < m; k += 16) {   // 16 tokens = 4 quad-loads
                    float4 v[4];
                    int tk[4];
#pragma unroll
                    for (int i = 0; i < 4; ++i) {
                        int t  = k + 4 * i + part;
                        tk[i]  = t;
                        int tc = (t < m) ? t : (m - 1);   // clamp: dup line
                        int idx = __shfl(r, tc);
                        v[i] = *(const float4*)(embH + (size_t)idx * EMB + sub * 8);
                    }
#pragma unroll
                    for (int i = 0; i < 4; ++i) {
                        if (tk[i] < m) {
                            const __half2* h = (const __half2*)&v[i];
#pragma unroll
                            for (int q = 0; q < 4; ++q) {
                                float2 f = __half22float2(h[q]);
                                acc[2 * q]     += f.x;
                                acc[2 * q + 1] += f.y;
                            }
                        }
                    }
                }
            }
#pragma unroll
            for (int j = 0; j < 8; ++j) {
                acc[j] += __shfl(acc[j], lane ^ 16);
                acc[j] += __shfl(acc[j], lane ^ 32);
            }
            if (part == 0) {
                const float inv = 1.0f / (float)len;
                float* dst = &bufA[s * (EMB + LPAD) + sub * 8];
                *(float4*)(dst)     = make_float4(acc[0] * inv, acc[1] * inv,
                                                  acc[2] * inv, acc[3] * inv);
                *(float4*)(dst + 4) = make_float4(acc[4] * inv, acc[5] * inv,
                                                  acc[6] * inv, acc[7] * inv);
            }
        } else {
            const int half = lane >> 5;
            const int col4 = (lane & 31) * 4;
            float4 acc = make_float4(0.f, 0.f, 0.f, 0.f);
            for (int c = 0; c < 4; ++c) {
                const int coff = c * 64;
                if (coff >= len) break;
                int m = len - coff;
                if (m > 64) m = 64;
                int r = r0;
                if (c == 1) r = r1;
                if (c == 2) r = r2;
                if (c == 3) r = r3;
                for (int k = 0; k < m; k += 16) {
                    float4 v[8];
#pragma unroll
                    for (int i = 0; i < 8; ++i) {
                        int t  = k + 2 * i + half;
                        int tc = (t < m) ? t : (m - 1);
                        int idx = __shfl(r, tc);
                        v[i] = *(const float4*)(emb + (size_t)idx * EMB + col4);
                    }
#pragma unroll
                    for (int i = 0; i < 8; ++i) {
                        if (k + 2 * i + half < m) {
                            acc.x += v[i].x; acc.y += v[i].y;
                            acc.z += v[i].z; acc.w += v[i].w;
                        }
                    }
                }
            }
            acc.x += __shfl(acc.x, lane ^ 32);
            acc.y += __shfl(acc.y, lane ^ 32);
            acc.z += __shfl(acc.z, lane ^ 32);
            acc.w += __shfl(acc.w, lane ^ 32);
            if (half == 0) {
                const float inv = 1.0f / (float)len;
                *(float4*)&bufA[s * (EMB + LPAD) + col4] =
                    make_float4(acc.x * inv, acc.y * inv, acc.z * inv, acc.w * inv);
            }
        }
    }
    __syncthreads();

    // ---- MLP phase (R7-proven) ----
    layerT<128, 512, 4, true>(bufA, bufB, Wt,         b1, tid);
    __syncthreads();
    layerT<512, 256, 4, true>(bufB, bufA, Wt + 16384, b2, tid);
    __syncthreads();
    layerT<256, 128, 2, true>(bufA, bufB, Wt + 49152, b3, tid);
    __syncthreads();

    if (tid < 2 * S_TILE) {
        int s = tid >> 1;
        int o = tid & 1;
        float accv = b4[o];
        const float* xr2 = &bufB[s * (EMB + LPAD)];
        const float* wr2 = &W4[(size_t)o * EMB];
#pragma unroll 8
        for (int f = 0; f < EMB; ++f) accv = fmaf(xr2[f], wr2[f], accv);
        out[(size_t)(base + s) * 2 + o] = accv;
    }
}

extern "C" void kernel_launch(void* const* d_in, const int* in_sizes, int n_in,
                              void* d_out, int out_size, void* d_ws, size_t ws_size,
                              hipStream_t stream)
{
    const int*   x       = (const int*)d_in[0];
    const int*   lengths = (const int*)d_in[1];
    const float* emb     = (const float*)d_in[2];
    const float* W1      = (const float*)d_in[3];
    const float* b1      = (const float*)d_in[4];
    const float* W2      = (const float*)d_in[5];
    const float* b2      = (const float*)d_in[6];
    const float* W3      = (const float*)d_in[7];
    const float* b3      = (const float*)d_in[8];
    const float* W4      = (const float*)d_in[9];
    const float* b4      = (const float*)d_in[10];
    float*       out     = (float*)d_out;

    float4* Wt   = (float4*)d_ws;
    __half* embH = (__half*)((char*)d_ws + EMBH_OFF);

    const int N = in_sizes[1];   // 4096
    const bool fp16 = (ws_size >= WS_NEED);   // R5 evidenced ws >= 34.8 MB

    if (fp16) {
        prep_kernel<<<6474, 256, 0, stream>>>(emb, W1, W2, W3, embH, Wt, 1);
        fused_kernel<true><<<N / S_TILE, 256, 0, stream>>>(
            x, lengths, emb, embH, Wt, b1, b2, b3, W4, b4, out);
    } else {
        prep_kernel<<<6474, 256, 0, stream>>>(emb, W1, W2, W3, embH, Wt, 0);
        fused_kernel<false><<<N / S_TILE, 256, 0, stream>>>(
            x, lengths, emb, embH, Wt, b1, b2, b3, W4, b4, out);
    }
}

// Round 9
// 169.656 us; speedup vs baseline: 1.3388x; 1.0309x over previous
//
#include <hip/hip_runtime.h>
#include <hip/hip_fp16.h>

#define T_TOK 200
#define EMB   128
#define S_TILE 8
#define LPAD  4

// ws layout: Wt (57344 float4 = 917504 B) | embH (100000*128*2 = 25600000 B)
#define WT_F4      57344
#define EMBH_OFF   917504UL
#define WS_NEED    (EMBH_OFF + 25600000UL)

// ---- prep: W transpose/pack + emb fp32->fp16 convert ----
__global__ __launch_bounds__(256) void prep_kernel(
    const float* __restrict__ emb,
    const float* __restrict__ W1, const float* __restrict__ W2,
    const float* __restrict__ W3,
    __half* __restrict__ embH, float4* __restrict__ ws4, int do_conv)
{
    int bid = blockIdx.x;
    if (bid < 6250) {
        if (!do_conv) return;
        size_t i = ((size_t)bid * 256 + threadIdx.x) * 8;   // 6250*256*8 = 12.8M exact
        float4 a = *(const float4*)(emb + i);
        float4 b = *(const float4*)(emb + i + 4);
        __half2 hh[4];
        hh[0] = __floats2half2_rn(a.x, a.y);
        hh[1] = __floats2half2_rn(a.z, a.w);
        hh[2] = __floats2half2_rn(b.x, b.y);
        hh[3] = __floats2half2_rn(b.z, b.w);
        *(float4*)(embH + i) = *(float4*)hh;
    } else {
        int j = (bid - 6250) * 256 + threadIdx.x;           // < 57344
        if (j < 16384) {
            int fc = j >> 9, o = j & 511;
            const float* s = W1 + (size_t)o * 128 + fc * 4;
            ws4[fc * 512 + o] = make_float4(s[0], s[1], s[2], s[3]);
        } else if (j < 49152) {
            int t = j - 16384;
            int fc = t >> 8, o = t & 255;
            const float* s = W2 + (size_t)o * 512 + fc * 4;
            ws4[16384 + fc * 256 + o] = make_float4(s[0], s[1], s[2], s[3]);
        } else {
            int t = j - 49152;
            int fc = t >> 7, o = t & 127;
            const float* s = W3 + (size_t)o * 256 + fc * 4;
            ws4[49152 + fc * 128 + o] = make_float4(s[0], s[1], s[2], s[3]);
        }
    }
}

// ---- layer with transposed-packed W, tunable outputs-per-thread (R7-proven) ----
template <int FIN, int FOUT, int OPT, bool RELU>
__device__ __forceinline__ void layerT(const float* __restrict__ sin,
                                       float* __restrict__ sout,
                                       const float4* __restrict__ Wt,
                                       const float* __restrict__ b, int tid)
{
    constexpr int SIN_STR  = FIN + LPAD;
    constexpr int SOUT_STR = FOUT + LPAD;
    constexpr int NO     = FOUT / OPT;
    constexpr int GROUPS = 256 / NO;
    constexpr int SPT    = S_TILE / GROUPS;

    const int o0 = tid % NO;
    const int s0 = (tid / NO) * SPT;

    float acc[OPT][SPT];
#pragma unroll
    for (int i = 0; i < OPT; ++i) {
        float bi = b[o0 + i * NO];
#pragma unroll
        for (int j = 0; j < SPT; ++j) acc[i][j] = bi;
    }

    float4 wc[OPT], wn[OPT];
#pragma unroll
    for (int i = 0; i < OPT; ++i) wc[i] = Wt[(size_t)0 * FOUT + o0 + i * NO];

    int f = 0;
    for (; f < FIN - 4; f += 4) {
        const int fc = (f >> 2) + 1;
#pragma unroll
        for (int i = 0; i < OPT; ++i) wn[i] = Wt[(size_t)fc * FOUT + o0 + i * NO];
#pragma unroll
        for (int j = 0; j < SPT; ++j) {
            float4 xv = *(const float4*)&sin[(s0 + j) * SIN_STR + f];
#pragma unroll
            for (int i = 0; i < OPT; ++i) {
                acc[i][j] = fmaf(xv.x, wc[i].x, acc[i][j]);
                acc[i][j] = fmaf(xv.y, wc[i].y, acc[i][j]);
                acc[i][j] = fmaf(xv.z, wc[i].z, acc[i][j]);
                acc[i][j] = fmaf(xv.w, wc[i].w, acc[i][j]);
            }
        }
#pragma unroll
        for (int i = 0; i < OPT; ++i) wc[i] = wn[i];
    }
#pragma unroll
    for (int j = 0; j < SPT; ++j) {
        float4 xv = *(const float4*)&sin[(s0 + j) * SIN_STR + f];
#pragma unroll
        for (int i = 0; i < OPT; ++i) {
            acc[i][j] = fmaf(xv.x, wc[i].x, acc[i][j]);
            acc[i][j] = fmaf(xv.y, wc[i].y, acc[i][j]);
            acc[i][j] = fmaf(xv.z, wc[i].z, acc[i][j]);
            acc[i][j] = fmaf(xv.w, wc[i].w, acc[i][j]);
        }
    }

#pragma unroll
    for (int j = 0; j < SPT; ++j) {
#pragma unroll
        for (int i = 0; i < OPT; ++i) {
            float v = acc[i][j];
            if (RELU) v = fmaxf(v, 0.f);
            sout[(s0 + j) * SOUT_STR + o0 + i * NO] = v;
        }
    }
}

// ---- Fused pool + MLP. fp16 pool: 32-token batches = 8 quad-loads in
// flight per wave (restores R7's MLP depth at half the bytes). ----
template <bool USE_FP16>
__global__ __launch_bounds__(256) void fused_kernel(
    const int* __restrict__ x, const int* __restrict__ lengths,
    const float* __restrict__ emb, const __half* __restrict__ embH,
    const float4* __restrict__ Wt,
    const float* __restrict__ b1, const float* __restrict__ b2,
    const float* __restrict__ b3,
    const float* __restrict__ W4, const float* __restrict__ b4,
    float* __restrict__ out)
{
    __shared__ float bufA[S_TILE * (256 + LPAD)];   // X (str 132), H2 (str 260)
    __shared__ float bufB[S_TILE * (512 + LPAD)];   // H1 (str 516), H3 (str 132)

    const int tid  = threadIdx.x;
    const int wid  = tid >> 6;
    const int lane = tid & 63;
    const int base = blockIdx.x * S_TILE;

    // ---- pool phase: wave wid pools samples 2*wid, 2*wid+1 ----
    for (int sl = 0; sl < 2; ++sl) {
        const int s   = wid * 2 + sl;
        const int n   = base + s;
        const int len = lengths[n];
        const int* xr = x + (size_t)n * T_TOK;

        int r0 = xr[lane];
        int r1 = xr[64 + lane];
        int r2 = xr[128 + lane];
        int r3 = xr[(192 + lane < T_TOK) ? (192 + lane) : (T_TOK - 1)];

        if (USE_FP16) {
            const int part = lane >> 4;          // token-of-quad
            const int sub  = lane & 15;          // cols [8*sub, 8*sub+8)
            float acc[8];
#pragma unroll
            for (int j = 0; j < 8; ++j) acc[j] = 0.f;

            for (int c = 0; c < 4; ++c) {
                const int coff = c * 64;
                if (coff >= len) break;
                int m = len - coff;
                if (m > 64) m = 64;
                int r = r0;
                if (c == 1) r = r1;
                if (c == 2) r = r2;
                if (c == 3) r = r3;

                for (int k = 0; k < m; k += 32) {   // 32 tokens = 8 quad-loads
                    float4 v[8];
                    int tk[8];
#pragma unroll
                    for (int i = 0; i < 8; ++i) {
                        int t  = k + 4 * i + part;          // <= 63
                        tk[i]  = t;
                        int tc = (t < m) ? t : (m - 1);     // clamp: dup line
                        int idx = __shfl(r, tc);
                        v[i] = *(const float4*)(embH + (size_t)idx * EMB + sub * 8);
                    }
#pragma unroll
                    for (int i = 0; i < 8; ++i) {
                        if (tk[i] < m) {
                            const __half2* h = (const __half2*)&v[i];
#pragma unroll
                            for (int q = 0; q < 4; ++q) {
                                float2 f = __half22float2(h[q]);
                                acc[2 * q]     += f.x;
                                acc[2 * q + 1] += f.y;
                            }
                        }
                    }
                }
            }
#pragma unroll
            for (int j = 0; j < 8; ++j) {
                acc[j] += __shfl(acc[j], lane ^ 16);
                acc[j] += __shfl(acc[j], lane ^ 32);
            }
            if (part == 0) {
                const float inv = 1.0f / (float)len;
                float* dst = &bufA[s * (EMB + LPAD) + sub * 8];
                *(float4*)(dst)     = make_float4(acc[0] * inv, acc[1] * inv,
                                                  acc[2] * inv, acc[3] * inv);
                *(float4*)(dst + 4) = make_float4(acc[4] * inv, acc[5] * inv,
                                                  acc[6] * inv, acc[7] * inv);
            }
        } else {
            const int half = lane >> 5;
            const int col4 = (lane & 31) * 4;
            float4 acc = make_float4(0.f, 0.f, 0.f, 0.f);
            for (int c = 0; c < 4; ++c) {
                const int coff = c * 64;
                if (coff >= len) break;
                int m = len - coff;
                if (m > 64) m = 64;
                int r = r0;
                if (c == 1) r = r1;
                if (c == 2) r = r2;
                if (c == 3) r = r3;
                for (int k = 0; k < m; k += 16) {
                    float4 v[8];
#pragma unroll
                    for (int i = 0; i < 8; ++i) {
                        int t  = k + 2 * i + half;
                        int tc = (t < m) ? t : (m - 1);
                        int idx = __shfl(r, tc);
                        v[i] = *(const float4*)(emb + (size_t)idx * EMB + col4);
                    }
#pragma unroll
                    for (int i = 0; i < 8; ++i) {
                        if (k + 2 * i + half < m) {
                            acc.x += v[i].x; acc.y += v[i].y;
                            acc.z += v[i].z; acc.w += v[i].w;
                        }
                    }
                }
            }
            acc.x += __shfl(acc.x, lane ^ 32);
            acc.y += __shfl(acc.y, lane ^ 32);
            acc.z += __shfl(acc.z, lane ^ 32);
            acc.w += __shfl(acc.w, lane ^ 32);
            if (half == 0) {
                const float inv = 1.0f / (float)len;
                *(float4*)&bufA[s * (EMB + LPAD) + col4] =
                    make_float4(acc.x * inv, acc.y * inv, acc.z * inv, acc.w * inv);
            }
        }
    }
    __syncthreads();

    // ---- MLP phase (R7-proven) ----
    layerT<128, 512, 4, true>(bufA, bufB, Wt,         b1, tid);
    __syncthreads();
    layerT<512, 256, 4, true>(bufB, bufA, Wt + 16384, b2, tid);
    __syncthreads();
    layerT<256, 128, 2, true>(bufA, bufB, Wt + 49152, b3, tid);
    __syncthreads();

    if (tid < 2 * S_TILE) {
        int s = tid >> 1;
        int o = tid & 1;
        float accv = b4[o];
        const float* xr2 = &bufB[s * (EMB + LPAD)];
        const float* wr2 = &W4[(size_t)o * EMB];
#pragma unroll 8
        for (int f = 0; f < EMB; ++f) accv = fmaf(xr2[f], wr2[f], accv);
        out[(size_t)(base + s) * 2 + o] = accv;
    }
}

extern "C" void kernel_launch(void* const* d_in, const int* in_sizes, int n_in,
                              void* d_out, int out_size, void* d_ws, size_t ws_size,
                              hipStream_t stream)
{
    const int*   x       = (const int*)d_in[0];
    const int*   lengths = (const int*)d_in[1];
    const float* emb     = (const float*)d_in[2];
    const float* W1      = (const float*)d_in[3];
    const float* b1      = (const float*)d_in[4];
    const float* W2      = (const float*)d_in[5];
    const float* b2      = (const float*)d_in[6];
    const float* W3      = (const float*)d_in[7];
    const float* b3      = (const float*)d_in[8];
    const float* W4      = (const float*)d_in[9];
    const float* b4      = (const float*)d_in[10];
    float*       out     = (float*)d_out;

    float4* Wt   = (float4*)d_ws;
    __half* embH = (__half*)((char*)d_ws + EMBH_OFF);

    const int N = in_sizes[1];   // 4096
    const bool fp16 = (ws_size >= WS_NEED);

    if (fp16) {
        prep_kernel<<<6474, 256, 0, stream>>>(emb, W1, W2, W3, embH, Wt, 1);
        fused_kernel<true><<<N / S_TILE, 256, 0, stream>>>(
            x, lengths, emb, embH, Wt, b1, b2, b3, W4, b4, out);
    } else {
        prep_kernel<<<6474, 256, 0, stream>>>(emb, W1, W2, W3, embH, Wt, 0);
        fused_kernel<false><<<N / S_TILE, 256, 0, stream>>>(
            x, lengths, emb, embH, Wt, b1, b2, b3, W4, b4, out);
    }
}